// Round 12
// baseline (4674.595 us; speedup 1.0000x reference)
//
#include <hip/hip_runtime.h>

#define BB 4
#define NN 8192
#define MM 2048
#define KK 32
#define RROWS (BB*MM*KK)   // 262144 rows (b,m,k)

// Exact per-op squared distance: matches numpy/XLA (no FMA contraction, axis-order sum).
__device__ __forceinline__ float dist2(float ax,float ay,float az,float bx,float by,float bz){
    float dx=__fsub_rn(ax,bx), dy=__fsub_rn(ay,by), dz=__fsub_rn(az,bz);
    return __fadd_rn(__fadd_rn(__fmul_rn(dx,dx),__fmul_rn(dy,dy)),__fmul_rn(dz,dz));
}

// ---------------- FPS v4: spatial cells + EXACT pruning ----------------
// R5-R9 post-mortem: every full-rescan variant costs ~2.3-2.7ms (8192 pts x 2047 steps
// of VALU+LDS is the work itself). Fix the WORK: sort points into 8x8x8 grid cells
// (16 sorted pts per thread-cell). Per step, skip cell iff provably no dmin changes:
// dist(a,center) >= r_cell + sqrt(cellmax_dmin)  (conservative f32 slack -> skip is a
// provable no-op -> dmin evolution bit-identical to reference). Skipped cells keep
// cached (cmax, candidate). Late steps touch ~1-3 cells/wave instead of 64.
// Tie-break: packed u64 (value<<32 | (8191-orig)<<13 | pos) == first-orig-index argmax.
__global__ __launch_bounds__(512, 2) void fps_kernel(const float* __restrict__ coords,
                                                     float* __restrict__ anchors)
{
    const int b = blockIdx.x, tid = threadIdx.x;
    const int lane = tid & 63, w = tid >> 6;
    const float* cb = coords + (size_t)b*NN*3;
    float* ab = anchors + (size_t)b*MM*3;

    __shared__ float sx[NN], sy[NN], sz[NN];      // sorted coords (SoA)  96 KB
    __shared__ float sdmin[NN];                   // 32 KB
    __shared__ unsigned short sidx[NN];           // sorted -> orig, 16 KB
    __shared__ unsigned int hist[512];
    __shared__ unsigned long long cellres[512];
    __shared__ unsigned long long slot[2][8];

    // ---- histogram over 9-bit grid key
    hist[tid] = 0u;
    __syncthreads();
    for(int j=0;j<16;++j){
        int p = tid*16+j;
        float x=cb[p*3+0], y=cb[p*3+1], z=cb[p*3+2];
        int kx=(int)(x*8.f); kx = kx>7?7:kx;
        int ky=(int)(y*8.f); ky = ky>7?7:ky;
        int kz=(int)(z*8.f); kz = kz>7?7:kz;
        atomicAdd(&hist[(kx<<6)|(ky<<3)|kz], 1u);
    }
    __syncthreads();
    // ---- exclusive prefix over 512 bins (wave 0)
    if(w==0){
        unsigned v[8], sum=0u;
#pragma unroll
        for(int k=0;k<8;++k) v[k]=hist[lane*8+k];
#pragma unroll
        for(int k=0;k<8;++k){ unsigned t=v[k]; v[k]=sum; sum+=t; }
        unsigned run = sum;
#pragma unroll
        for(int d=1;d<64;d<<=1){ unsigned q=__shfl_up(run,d); if(lane>=d) run+=q; }
        unsigned base = run - sum;
#pragma unroll
        for(int k=0;k<8;++k) hist[lane*8+k] = base + v[k];
    }
    __syncthreads();
    // ---- scatter into sorted order (intra-cell order arbitrary: all uses are
    //      set-functions with explicit orig-idx tie-break -> run-deterministic results)
    for(int j=0;j<16;++j){
        int p = tid*16+j;
        float x=cb[p*3+0], y=cb[p*3+1], z=cb[p*3+2];
        int kx=(int)(x*8.f); kx = kx>7?7:kx;
        int ky=(int)(y*8.f); ky = ky>7?7:ky;
        int kz=(int)(z*8.f); kz = kz>7?7:kz;
        unsigned pos = atomicAdd(&hist[(kx<<6)|(ky<<3)|kz], 1u);
        sx[pos]=x; sy[pos]=y; sz[pos]=z; sidx[pos]=(unsigned short)p;
    }
    __syncthreads();
    // ---- cell init: thread t owns sorted range [t*16, t*16+16)
    float mnx=1e30f,mny=1e30f,mnz=1e30f,mxx=-1e30f,mxy=-1e30f,mxz=-1e30f;
#pragma unroll
    for(int j=0;j<16;++j){
        int p=tid*16+j;
        float x=sx[p], y=sy[p], z=sz[p];
        mnx=fminf(mnx,x); mxx=fmaxf(mxx,x);
        mny=fminf(mny,y); mxy=fmaxf(mxy,y);
        mnz=fminf(mnz,z); mxz=fmaxf(mxz,z);
        sdmin[p]=1e10f;
    }
    float ccx=0.5f*(mnx+mxx), ccy=0.5f*(mny+mxy), ccz=0.5f*(mnz+mxz);
    float r2m=0.f;
    unsigned bestlow=0u;
#pragma unroll
    for(int j=0;j<16;++j){
        int p=tid*16+j;
        float dx=sx[p]-ccx, dy=sy[p]-ccy, dz=sz[p]-ccz;
        float d2c=dx*dx+dy*dy+dz*dz;
        r2m = fmaxf(r2m, d2c);
        unsigned lowj = (((unsigned)(8191 - (int)sidx[p]))<<13) | (unsigned)p;
        bestlow = (lowj>bestlow)?lowj:bestlow;
    }
    const float rr = sqrtf(r2m)*1.0001f + 1e-9f;   // inflated: covers all rounding
    float cmax = 1e10f;
    unsigned long long cand = ((unsigned long long)__float_as_uint(1e10f)<<32) | bestlow;
    float cthr = 3.0e38f;                          // step 1: everything kept
    float lx=cb[0], ly=cb[1], lz=cb[2];
    if(tid==0){ ab[0]=lx; ab[1]=ly; ab[2]=lz; }
    __syncthreads();

    for(int s=1;s<MM;++s){
        // conservative keep test (any math: slack 1.0002 >> cumulative f32 error)
        float tdx=ccx-lx, tdy=ccy-ly, tdz=ccz-lz;
        float t2 = tdx*tdx+tdy*tdy+tdz*tdz;
        bool kept = t2 < cthr;
        unsigned long long mask = __ballot(kept);   // wave-uniform
        while(mask){
            int c0=(int)__builtin_ctzll(mask); mask &= mask-1ull;
            int c1=c0,c2=c0,c3=c0;
            if(mask){ c1=(int)__builtin_ctzll(mask); mask &= mask-1ull; }
            if(mask){ c2=(int)__builtin_ctzll(mask); mask &= mask-1ull; }
            if(mask){ c3=(int)__builtin_ctzll(mask); mask &= mask-1ull; }
            int g = lane>>4;
            int cc = (g==0)?c0:((g==1)?c1:((g==2)?c2:c3));
            int p = ((w<<6)+cc)*16 + (lane&15);
            float x=sx[p], y=sy[p], z=sz[p];
            float dm=sdmin[p];
            float d = dist2(x,y,z,lx,ly,lz);        // EXACT path
            float nd = fminf(dm,d);                 // jnp.minimum
            sdmin[p]=nd;
            unsigned oi = sidx[p];
            unsigned long long pkt = ((unsigned long long)__float_as_uint(nd)<<32)
                                   | (((unsigned)(8191u-oi))<<13) | (unsigned)p;
#pragma unroll
            for(int off=1; off<16; off<<=1){        // argmax within 16-lane group
                unsigned long long q = __shfl_xor(pkt, off);
                if(q>pkt) pkt=q;
            }
            if((lane&15)==0) cellres[(w<<6)+cc] = pkt;
        }
        asm volatile("s_waitcnt lgkmcnt(0)" ::: "memory");  // in-wave ds_write->ds_read order
        if(kept){
            unsigned long long pkt = cellres[tid];
            cand = pkt;
            cmax = __uint_as_float((unsigned)(pkt>>32));
            float q = rr + sqrtf(cmax);
            cthr = q*q*1.0002f;
        }
        // wave argmax over 64 cached cells: f32 value max, then u32 low max among ties
        float v = cmax;
#pragma unroll
        for(int off=1;off<64;off<<=1) v = fmaxf(v, __shfl_xor(v,off));
        unsigned lowm = (cmax==v) ? (unsigned)cand : 0u;
#pragma unroll
        for(int off=1;off<64;off<<=1){ unsigned q=__shfl_xor(lowm,off); lowm = (q>lowm)?q:lowm; }
        const int par = s&1;
        if(lane==0) slot[par][w] = ((unsigned long long)__float_as_uint(v)<<32) | lowm;
        __syncthreads();
        unsigned long long p0=slot[par][0],p1=slot[par][1],p2=slot[par][2],p3=slot[par][3];
        unsigned long long p4=slot[par][4],p5=slot[par][5],p6=slot[par][6],p7=slot[par][7];
        if(p1>p0)p0=p1;
        if(p3>p2)p2=p3;
        if(p5>p4)p4=p5;
        if(p7>p6)p6=p7;
        if(p2>p0)p0=p2;
        if(p6>p4)p4=p6;
        if(p4>p0)p0=p4;
        int pos = (int)((unsigned)p0 & 0x1FFFu);
        lx=sx[pos]; ly=sy[pos]; lz=sz[pos];         // broadcast (uniform addr)
        if(tid==0){ ab[s*3+0]=lx; ab[s*3+1]=ly; ab[s*3+2]=lz; }
    }
}

// ---------------- Ball query: 1 wave per anchor, ballot compaction ----------------
__global__ __launch_bounds__(256) void ballq_kernel(const float* __restrict__ coords,
                                                    const float* __restrict__ anchors,
                                                    int* __restrict__ nb)
{
    const int wid = threadIdx.x>>6, lane = threadIdx.x&63;
    const int a = blockIdx.x*4 + wid;            // 0..B*M-1
    const int b = a >> 11;                       // / MM
    const float* cb = coords + (size_t)b*NN*3;
    const float ax=anchors[a*3+0], ay=anchors[a*3+1], az=anchors[a*3+2];
    const float R2 = (float)(0.2*0.2);           // f64 product -> f32, matches JAX promotion
    int* out = nb + (size_t)a*KK;
    int cnt = 0, first = 0;
    for(int base=0; base<NN; base+=64){
        int i = base + lane;
        float d2 = dist2(ax,ay,az, cb[i*3+0],cb[i*3+1],cb[i*3+2]);
        bool in = d2 < R2;
        unsigned long long mask = __ballot(in);
        if(cnt==0 && mask) first = base + (int)__builtin_ctzll(mask);
        int pre = __popcll(mask & ((1ull<<lane)-1ull));
        if(in && (cnt+pre)<KK) out[cnt+pre] = i;
        cnt += __popcll(mask);
        if(cnt>=KK) break;
    }
    if(cnt<KK && lane>=cnt && lane<KK) out[lane] = first; // pad with first hit
}

// ---------------- Layer-0 stats pass (compute y0, discard, accumulate sum/sumsq) ----------------
__global__ __launch_bounds__(256) void l0_stats_kernel(
    const float* __restrict__ coords, const float* __restrict__ feats,
    const float* __restrict__ anchors, const int* __restrict__ nb,
    const float* __restrict__ W0, float* __restrict__ stats)
{
    const int r = blockIdx.x*256 + threadIdx.x;
    const int b = r>>16, mk = r&65535, m = mk>>5;
    const int p = nb[r];
    const float* pc = coords + ((size_t)b*NN + p)*3;
    const float* pa = anchors + ((size_t)b*MM + m)*3;
    const float* pf = feats + ((size_t)b*NN + p)*16;
    float x[19];
    x[0]=pc[0]-pa[0]; x[1]=pc[1]-pa[1]; x[2]=pc[2]-pa[2];
#pragma unroll
    for(int c=0;c<16;++c) x[3+c]=pf[c];
    __shared__ float lsum[4][64], lsq[4][64];
    const int lane = threadIdx.x&63, wid = threadIdx.x>>6;
    for(int o=0;o<64;++o){
        const float* w = W0 + o*19;
        float acc=0.f;
#pragma unroll
        for(int c=0;c<19;++c) acc = fmaf(x[c], w[c], acc);
        float s1=acc, s2=acc*acc;
#pragma unroll
        for(int off=32;off>0;off>>=1){ s1+=__shfl_xor(s1,off); s2+=__shfl_xor(s2,off); }
        if(lane==0){ lsum[wid][o]=s1; lsq[wid][o]=s2; }
    }
    __syncthreads();
    if(threadIdx.x<64){
        int o=threadIdx.x;
        atomicAdd(&stats[o],    lsum[0][o]+lsum[1][o]+lsum[2][o]+lsum[3][o]);
        atomicAdd(&stats[64+o], lsq[0][o]+lsq[1][o]+lsq[2][o]+lsq[3][o]);
    }
}

// ---------------- Finalize BN constants: s = g*rsqrt(var+eps), sh = b - mu*s ----------------
__global__ void fin_kernel(const float* __restrict__ acc, const float* __restrict__ g,
                           const float* __restrict__ bias, float* __restrict__ s,
                           float* __restrict__ sh, int C)
{
    int o = threadIdx.x; if(o>=C) return;
    const float R = (float)RROWS;
    float mu = acc[o]/R;
    float var = acc[C+o]/R - mu*mu;
    if(var<0.f) var=0.f;
    float sc = g[o] * (1.0f/sqrtf(var+1e-5f));
    s[o]=sc; sh[o]=bias[o]-mu*sc;
}

// ---------------- Layer-1: recompute y0, BN0+ReLU, y1 -> ws (transposed [o][r]), stats1 ----------------
__global__ __launch_bounds__(256) void l1_kernel(
    const float* __restrict__ coords, const float* __restrict__ feats,
    const float* __restrict__ anchors, const int* __restrict__ nb,
    const float* __restrict__ W0, const float* __restrict__ W1,
    const float* __restrict__ s0, const float* __restrict__ sh0,
    float* __restrict__ y1, float* __restrict__ stats)
{
    const int r = blockIdx.x*256 + threadIdx.x;
    const int b = r>>16, mk = r&65535, m = mk>>5;
    const int p = nb[r];
    const float* pc = coords + ((size_t)b*NN + p)*3;
    const float* pa = anchors + ((size_t)b*MM + m)*3;
    const float* pf = feats + ((size_t)b*NN + p)*16;
    float x[19];
    x[0]=pc[0]-pa[0]; x[1]=pc[1]-pa[1]; x[2]=pc[2]-pa[2];
#pragma unroll
    for(int c=0;c<16;++c) x[3+c]=pf[c];
    float x1[64];
#pragma unroll
    for(int o=0;o<64;++o){          // fully unrolled: x1 stays in registers (rule #20)
        const float* w = W0 + o*19;
        float acc=0.f;
#pragma unroll
        for(int c=0;c<19;++c) acc = fmaf(x[c], w[c], acc);
        x1[o] = fmaxf(fmaf(acc, s0[o], sh0[o]), 0.f);
    }
    __shared__ float lsum[4][64], lsq[4][64];
    const int lane = threadIdx.x&63, wid = threadIdx.x>>6;
    for(int o=0;o<64;++o){
        const float* w = W1 + o*64;
        float acc=0.f;
#pragma unroll
        for(int c=0;c<64;++c) acc = fmaf(x1[c], w[c], acc);
        y1[(size_t)o*RROWS + r] = acc;          // coalesced: lanes write consecutive r
        float s1=acc, s2=acc*acc;
#pragma unroll
        for(int off=32;off>0;off>>=1){ s1+=__shfl_xor(s1,off); s2+=__shfl_xor(s2,off); }
        if(lane==0){ lsum[wid][o]=s1; lsq[wid][o]=s2; }
    }
    __syncthreads();
    if(threadIdx.x<64){
        int o=threadIdx.x;
        atomicAdd(&stats[128+o], lsum[0][o]+lsum[1][o]+lsum[2][o]+lsum[3][o]);
        atomicAdd(&stats[192+o], lsq[0][o]+lsq[1][o]+lsq[2][o]+lsq[3][o]);
    }
}

// ---------------- Layer-2: BN1+ReLU, y2 (not stored): stats2 + per-(b,m,o) max/min over k ----------------
__global__ __launch_bounds__(256) void l2_kernel(
    const float* __restrict__ y1, const float* __restrict__ W2,
    const float* __restrict__ s1, const float* __restrict__ sh1,
    float* __restrict__ maxv, float* __restrict__ minv, float* __restrict__ stats)
{
    const int r = blockIdx.x*256 + threadIdx.x;
    float x1[64];
#pragma unroll
    for(int c=0;c<64;++c)                        // coalesced: lanes read consecutive r
        x1[c] = fmaxf(fmaf(y1[(size_t)c*RROWS + r], s1[c], sh1[c]), 0.f);
    __shared__ float lsum[4][128], lsq[4][128];
    const int lane = threadIdx.x&63, wid = threadIdx.x>>6;
    const size_t g = (size_t)(r>>5);   // (b,m) group: K=32 consecutive rows
    for(int o=0;o<128;++o){
        const float* w = W2 + o*64;
        float acc=0.f;
#pragma unroll
        for(int c=0;c<64;++c) acc = fmaf(x1[c], w[c], acc);
        float mx=acc, mn=acc;
#pragma unroll
        for(int off=16;off>0;off>>=1){ mx=fmaxf(mx,__shfl_xor(mx,off)); mn=fminf(mn,__shfl_xor(mn,off)); }
        float s1v=acc, s2v=acc*acc;
#pragma unroll
        for(int off=32;off>0;off>>=1){ s1v+=__shfl_xor(s1v,off); s2v+=__shfl_xor(s2v,off); }
        if((lane&31)==0){ maxv[g*128+o]=mx; minv[g*128+o]=mn; }
        if(lane==0){ lsum[wid][o]=s1v; lsq[wid][o]=s2v; }
    }
    __syncthreads();
    if(threadIdx.x<128){
        int o=threadIdx.x;
        atomicAdd(&stats[256+o], lsum[0][o]+lsum[1][o]+lsum[2][o]+lsum[3][o]);
        atomicAdd(&stats[384+o], lsq[0][o]+lsq[1][o]+lsq[2][o]+lsq[3][o]);
    }
}

// ---------------- Output: relu(s*pick+sh) where pick = max if s>=0 else min (exact commute) ----------------
__global__ __launch_bounds__(128) void out_kernel(
    const float* __restrict__ maxv, const float* __restrict__ minv,
    const float* __restrict__ s2, const float* __restrict__ sh2,
    float* __restrict__ agg)
{
    const int gg = blockIdx.x;     // 0..B*M-1
    const int o = threadIdx.x;     // 128
    float s = s2[o], sh = sh2[o];
    float pick = (s >= 0.f) ? maxv[(size_t)gg*128+o] : minv[(size_t)gg*128+o];
    float v = fmaxf(fmaf(pick, s, sh), 0.f);
    const int b = gg>>11, m = gg&2047;
    agg[((size_t)b*128 + o)*MM + m] = v;
}

extern "C" void kernel_launch(void* const* d_in, const int* in_sizes, int n_in,
                              void* d_out, int out_size, void* d_ws, size_t ws_size,
                              hipStream_t stream) {
    (void)in_sizes; (void)n_in; (void)out_size; (void)ws_size;
    const float* coords = (const float*)d_in[0];
    const float* feats  = (const float*)d_in[1];
    const float* W0 = (const float*)d_in[2];
    const float* g0 = (const float*)d_in[3];
    const float* b0 = (const float*)d_in[4];
    const float* W1 = (const float*)d_in[5];
    const float* g1 = (const float*)d_in[6];
    const float* b1 = (const float*)d_in[7];
    const float* W2 = (const float*)d_in[8];
    const float* g2 = (const float*)d_in[9];
    const float* b2 = (const float*)d_in[10];

    float* out = (float*)d_out;
    float* anchors = out;                      // [B,M,3]
    float* agg = out + (size_t)BB*MM*3;        // [B,128,M]

    // workspace layout (~73 MB)
    char* ws = (char*)d_ws;
    int*   nb    = (int*)ws;                                       // 262144 ints
    float* y1v   = (float*)(ws + 1048576);                         // 64 x RROWS f32 (transposed)
    float* maxv  = (float*)(ws + 1048576 + 67108864);              // B*M*128
    float* minv  = maxv + (size_t)BB*MM*128;
    float* stats = minv + (size_t)BB*MM*128;                       // 512 floats accum
    float* s0 = stats + 512; float* sh0 = s0 + 64;
    float* s1 = sh0 + 64;    float* sh1 = s1 + 64;
    float* s2 = sh1 + 64;    float* sh2 = s2 + 128;

    hipMemsetAsync(stats, 0, 512*sizeof(float), stream);
    fps_kernel  <<<BB, 512, 0, stream>>>(coords, anchors);
    ballq_kernel<<<BB*MM/4, 256, 0, stream>>>(coords, anchors, nb);
    l0_stats_kernel<<<RROWS/256, 256, 0, stream>>>(coords, feats, anchors, nb, W0, stats);
    fin_kernel  <<<1, 64, 0, stream>>>(stats, g0, b0, s0, sh0, 64);
    l1_kernel   <<<RROWS/256, 256, 0, stream>>>(coords, feats, anchors, nb, W0, W1, s0, sh0, y1v, stats);
    fin_kernel  <<<1, 64, 0, stream>>>(stats+128, g1, b1, s1, sh1, 64);
    l2_kernel   <<<RROWS/256, 256, 0, stream>>>(y1v, W2, s1, sh1, maxv, minv, stats);
    fin_kernel  <<<1, 128, 0, stream>>>(stats+256, g2, b2, s2, sh2, 128);
    out_kernel  <<<BB*MM, 128, 0, stream>>>(maxv, minv, s2, sh2, agg);
}

// Round 13
// 3593.874 us; speedup vs baseline: 1.3007x; 1.3007x over previous
//
#include <hip/hip_runtime.h>

#define BB 4
#define NN 8192
#define MM 2048
#define KK 32
#define RROWS (BB*MM*KK)   // 262144 rows (b,m,k)

// Exact per-op squared distance: matches numpy/XLA (no FMA contraction, axis-order sum).
__device__ __forceinline__ float dist2(float ax,float ay,float az,float bx,float by,float bz){
    float dx=__fsub_rn(ax,bx), dy=__fsub_rn(ay,by), dz=__fsub_rn(az,bz);
    return __fadd_rn(__fadd_rn(__fmul_rn(dx,dx),__fmul_rn(dy,dy)),__fmul_rn(dz,dz));
}

// u32 max via DPP (values are non-negative f32 bits -> bit order == value order).
// old = r so masked/invalid lanes reduce as identity.
#define DPP_UMAX(r, CTRL, RM) do { \
    unsigned _t = (unsigned)__builtin_amdgcn_update_dpp((int)(r), (int)(r), (CTRL), (RM), 0xF, false); \
    (r) = (_t > (r)) ? _t : (r); } while(0)

// ---------------- FPS v5: thread-per-cell exact pruning + DPP argmax ----------------
// v4 post-mortem: pruning worked but the executor regressed (scattered 16-lane group
// reads = 512K bank conflicts; u64 shfl chains + cellres round-trip ~2x'd the serial
// tail). v5: one THREAD per 16-pt sorted range -- scan in registers + own aligned LDS
// block (stride 68 dwords: 16B-aligned b128, banks tiled evenly); per-cell cache in
// registers; wave argmax via VALU-speed DPP u32-max + ballot/readlane tie loop.
// Pruning/caching math identical to v4 (passed, exact): skip iff
// dist2(anchor,center) >= (rr+sqrt(cmax))^2*1.0002 -> provable no-op.
// Tie-break low word ((8191-orig)<<13|pos): u64 max == first-original-index argmax.
__global__ __launch_bounds__(512, 2) void fps_kernel(const float* __restrict__ coords,
                                                     float* __restrict__ anchors)
{
    const int b = blockIdx.x, tid = threadIdx.x;
    const int lane = tid & 63, w = tid >> 6;
    const float* cb = coords + (size_t)b*NN*3;
    float* ab = anchors + (size_t)b*MM*3;

    __shared__ float c4[512*68];                 // (x,y,z,dmin)/pt, cell stride 68 dw: 136KB... 139,264B
    __shared__ unsigned short sidx[NN];          // sorted -> orig (dead after prologue), 16KB
    __shared__ unsigned int hist[512];           // 2KB
    __shared__ unsigned long long slot[2][8];

    // ---- histogram over 9-bit grid key
    hist[tid] = 0u;
    __syncthreads();
#pragma unroll
    for(int j=0;j<16;++j){
        int p = tid*16+j;
        float x=cb[p*3+0], y=cb[p*3+1], z=cb[p*3+2];
        int kx=(int)(x*8.f); kx=kx>7?7:kx;
        int ky=(int)(y*8.f); ky=ky>7?7:ky;
        int kz=(int)(z*8.f); kz=kz>7?7:kz;
        atomicAdd(&hist[(kx<<6)|(ky<<3)|kz], 1u);
    }
    __syncthreads();
    // ---- exclusive prefix over 512 bins (wave 0)
    if(w==0){
        unsigned v[8], sum=0u;
#pragma unroll
        for(int k=0;k<8;++k) v[k]=hist[lane*8+k];
#pragma unroll
        for(int k=0;k<8;++k){ unsigned t=v[k]; v[k]=sum; sum+=t; }
        unsigned run = sum;
#pragma unroll
        for(int d=1;d<64;d<<=1){ unsigned q=__shfl_up(run,d); if(lane>=d) run+=q; }
        unsigned base = run - sum;
#pragma unroll
        for(int k=0;k<8;++k) hist[lane*8+k] = base + v[k];
    }
    __syncthreads();
    // ---- scatter (intra-cell order arbitrary; results deterministic via orig-idx tie-break)
#pragma unroll
    for(int j=0;j<16;++j){
        int p = tid*16+j;
        float x=cb[p*3+0], y=cb[p*3+1], z=cb[p*3+2];
        int kx=(int)(x*8.f); kx=kx>7?7:kx;
        int ky=(int)(y*8.f); ky=ky>7?7:ky;
        int kz=(int)(z*8.f); kz=kz>7?7:kz;
        unsigned pos = atomicAdd(&hist[(kx<<6)|(ky<<3)|kz], 1u);
        int a = (int)(pos>>4)*68 + (int)(pos&15)*4;
        c4[a+0]=x; c4[a+1]=y; c4[a+2]=z; c4[a+3]=1e10f;
        sidx[pos]=(unsigned short)p;
    }
    __syncthreads();
    // ---- prologue: own-range bounding sphere + static low words
    const int base = tid*68;
    float mnx=1e30f,mny=1e30f,mnz=1e30f,mxx=-1e30f,mxy=-1e30f,mxz=-1e30f;
#pragma unroll
    for(int j=0;j<16;++j){
        const float4 f = *(const float4*)&c4[base+4*j];
        mnx=fminf(mnx,f.x); mxx=fmaxf(mxx,f.x);
        mny=fminf(mny,f.y); mxy=fmaxf(mxy,f.y);
        mnz=fminf(mnz,f.z); mxz=fmaxf(mxz,f.z);
    }
    const float ccx=0.5f*(mnx+mxx), ccy=0.5f*(mny+mxy), ccz=0.5f*(mnz+mxz);
    float r2m=0.f;
    unsigned lowreg[16];
#pragma unroll
    for(int j=0;j<16;++j){
        const float4 f = *(const float4*)&c4[base+4*j];
        float dx=f.x-ccx, dy=f.y-ccy, dz=f.z-ccz;
        r2m = fmaxf(r2m, dx*dx+dy*dy+dz*dz);
        lowreg[j] = ((8191u-(unsigned)sidx[tid*16+j])<<13) | (unsigned)(tid*16+j);
    }
    const float rr = sqrtf(r2m)*1.0001f + 1e-9f;  // inflated: covers all rounding
    unsigned vbits = __float_as_uint(1e10f);      // cached cell max dmin (bits)
    unsigned candlo = 0u;                         // cached cell argmax low word
    float cthr = 3.0e38f;                         // step 1: everything scanned
    float lx=cb[0], ly=cb[1], lz=cb[2];
    if(tid==0){ ab[0]=lx; ab[1]=ly; ab[2]=lz; }

    for(int s=1;s<MM;++s){
        // conservative keep test (slack 1.0002 >> f32 rounding; skip => provable no-op)
        float tdx=ccx-lx, tdy=ccy-ly, tdz=ccz-lz;
        float t2 = tdx*tdx+tdy*tdy+tdz*tdz;
        if(t2 < cthr){
            unsigned bh=0u, bl=0u;
#pragma unroll
            for(int j=0;j<16;++j){
                const float4 f = *(const float4*)&c4[base+4*j];
                float d  = dist2(f.x,f.y,f.z, lx,ly,lz);   // EXACT path
                float nd = fminf(f.w, d);                  // jnp.minimum
                c4[base+4*j+3] = nd;
                unsigned vb = __float_as_uint(nd), lo = lowreg[j];
                bool gt = (vb > bh) || (vb == bh && lo > bl);
                bh = gt ? vb : bh;  bl = gt ? lo : bl;
            }
            vbits = bh; candlo = bl;
            float q = rr + sqrtf(__uint_as_float(bh));
            cthr = q*q*1.0002f;
        }
        // wave argmax: DPP u32 max over vbits (non-negative f32 bits), then tie loop
        unsigned rmx = vbits;
        DPP_UMAX(rmx, 0x111, 0xF);   // row_shr:1
        DPP_UMAX(rmx, 0x112, 0xF);   // row_shr:2
        DPP_UMAX(rmx, 0x114, 0xF);   // row_shr:4
        DPP_UMAX(rmx, 0x118, 0xF);   // row_shr:8
        DPP_UMAX(rmx, 0x142, 0xA);   // row_bcast:15
        DPP_UMAX(rmx, 0x143, 0xC);   // row_bcast:31  -> lane 63 has wave max
        unsigned uvmax = (unsigned)__builtin_amdgcn_readlane((int)rmx, 63);
        unsigned long long cm = __ballot(vbits == uvmax);
        unsigned bestlow = 0u;
        while(cm){                    // uniform trip count; ~1 iter (exact tie handling)
            int l = (int)__builtin_ctzll(cm); cm &= cm-1ull;
            unsigned lo = (unsigned)__builtin_amdgcn_readlane((int)candlo, l);
            bestlow = lo>bestlow ? lo : bestlow;
        }
        const int par = s&1;
        if(lane==0) slot[par][w] = ((unsigned long long)uvmax<<32) | bestlow;
        __syncthreads();
        unsigned long long p0=slot[par][0],p1=slot[par][1],p2=slot[par][2],p3=slot[par][3];
        unsigned long long p4=slot[par][4],p5=slot[par][5],p6=slot[par][6],p7=slot[par][7];
        if(p1>p0)p0=p1;
        if(p3>p2)p2=p3;
        if(p5>p4)p4=p5;
        if(p7>p6)p6=p7;
        if(p2>p0)p0=p2;
        if(p6>p4)p4=p6;
        if(p4>p0)p0=p4;
        const int pos = (int)((unsigned)p0 & 0x1FFFu);
        const int wa = (pos>>4)*68 + (pos&15)*4;   // uniform LDS addr -> broadcast
        lx=c4[wa+0]; ly=c4[wa+1]; lz=c4[wa+2];
        if(tid==0){ ab[s*3+0]=lx; ab[s*3+1]=ly; ab[s*3+2]=lz; }
    }
}

// ---------------- Ball query: 1 wave per anchor, ballot compaction ----------------
__global__ __launch_bounds__(256) void ballq_kernel(const float* __restrict__ coords,
                                                    const float* __restrict__ anchors,
                                                    int* __restrict__ nb)
{
    const int wid = threadIdx.x>>6, lane = threadIdx.x&63;
    const int a = blockIdx.x*4 + wid;            // 0..B*M-1
    const int b = a >> 11;                       // / MM
    const float* cb = coords + (size_t)b*NN*3;
    const float ax=anchors[a*3+0], ay=anchors[a*3+1], az=anchors[a*3+2];
    const float R2 = (float)(0.2*0.2);           // f64 product -> f32, matches JAX promotion
    int* out = nb + (size_t)a*KK;
    int cnt = 0, first = 0;
    for(int base=0; base<NN; base+=64){
        int i = base + lane;
        float d2 = dist2(ax,ay,az, cb[i*3+0],cb[i*3+1],cb[i*3+2]);
        bool in = d2 < R2;
        unsigned long long mask = __ballot(in);
        if(cnt==0 && mask) first = base + (int)__builtin_ctzll(mask);
        int pre = __popcll(mask & ((1ull<<lane)-1ull));
        if(in && (cnt+pre)<KK) out[cnt+pre] = i;
        cnt += __popcll(mask);
        if(cnt>=KK) break;
    }
    if(cnt<KK && lane>=cnt && lane<KK) out[lane] = first; // pad with first hit
}

// ---------------- Layer-0 stats pass (compute y0, discard, accumulate sum/sumsq) ----------------
__global__ __launch_bounds__(256) void l0_stats_kernel(
    const float* __restrict__ coords, const float* __restrict__ feats,
    const float* __restrict__ anchors, const int* __restrict__ nb,
    const float* __restrict__ W0, float* __restrict__ stats)
{
    const int r = blockIdx.x*256 + threadIdx.x;
    const int b = r>>16, mk = r&65535, m = mk>>5;
    const int p = nb[r];
    const float* pc = coords + ((size_t)b*NN + p)*3;
    const float* pa = anchors + ((size_t)b*MM + m)*3;
    const float* pf = feats + ((size_t)b*NN + p)*16;
    float x[19];
    x[0]=pc[0]-pa[0]; x[1]=pc[1]-pa[1]; x[2]=pc[2]-pa[2];
#pragma unroll
    for(int c=0;c<16;++c) x[3+c]=pf[c];
    __shared__ float lsum[4][64], lsq[4][64];
    const int lane = threadIdx.x&63, wid = threadIdx.x>>6;
    for(int o=0;o<64;++o){
        const float* w = W0 + o*19;
        float acc=0.f;
#pragma unroll
        for(int c=0;c<19;++c) acc = fmaf(x[c], w[c], acc);
        float s1=acc, s2=acc*acc;
#pragma unroll
        for(int off=32;off>0;off>>=1){ s1+=__shfl_xor(s1,off); s2+=__shfl_xor(s2,off); }
        if(lane==0){ lsum[wid][o]=s1; lsq[wid][o]=s2; }
    }
    __syncthreads();
    if(threadIdx.x<64){
        int o=threadIdx.x;
        atomicAdd(&stats[o],    lsum[0][o]+lsum[1][o]+lsum[2][o]+lsum[3][o]);
        atomicAdd(&stats[64+o], lsq[0][o]+lsq[1][o]+lsq[2][o]+lsq[3][o]);
    }
}

// ---------------- Finalize BN constants: s = g*rsqrt(var+eps), sh = b - mu*s ----------------
__global__ void fin_kernel(const float* __restrict__ acc, const float* __restrict__ g,
                           const float* __restrict__ bias, float* __restrict__ s,
                           float* __restrict__ sh, int C)
{
    int o = threadIdx.x; if(o>=C) return;
    const float R = (float)RROWS;
    float mu = acc[o]/R;
    float var = acc[C+o]/R - mu*mu;
    if(var<0.f) var=0.f;
    float sc = g[o] * (1.0f/sqrtf(var+1e-5f));
    s[o]=sc; sh[o]=bias[o]-mu*sc;
}

// ---------------- Layer-1: recompute y0, BN0+ReLU, y1 -> ws (transposed [o][r]), stats1 ----------------
__global__ __launch_bounds__(256) void l1_kernel(
    const float* __restrict__ coords, const float* __restrict__ feats,
    const float* __restrict__ anchors, const int* __restrict__ nb,
    const float* __restrict__ W0, const float* __restrict__ W1,
    const float* __restrict__ s0, const float* __restrict__ sh0,
    float* __restrict__ y1, float* __restrict__ stats)
{
    const int r = blockIdx.x*256 + threadIdx.x;
    const int b = r>>16, mk = r&65535, m = mk>>5;
    const int p = nb[r];
    const float* pc = coords + ((size_t)b*NN + p)*3;
    const float* pa = anchors + ((size_t)b*MM + m)*3;
    const float* pf = feats + ((size_t)b*NN + p)*16;
    float x[19];
    x[0]=pc[0]-pa[0]; x[1]=pc[1]-pa[1]; x[2]=pc[2]-pa[2];
#pragma unroll
    for(int c=0;c<16;++c) x[3+c]=pf[c];
    float x1[64];
#pragma unroll
    for(int o=0;o<64;++o){          // fully unrolled: x1 stays in registers (rule #20)
        const float* w = W0 + o*19;
        float acc=0.f;
#pragma unroll
        for(int c=0;c<19;++c) acc = fmaf(x[c], w[c], acc);
        x1[o] = fmaxf(fmaf(acc, s0[o], sh0[o]), 0.f);
    }
    __shared__ float lsum[4][64], lsq[4][64];
    const int lane = threadIdx.x&63, wid = threadIdx.x>>6;
    for(int o=0;o<64;++o){
        const float* w = W1 + o*64;
        float acc=0.f;
#pragma unroll
        for(int c=0;c<64;++c) acc = fmaf(x1[c], w[c], acc);
        y1[(size_t)o*RROWS + r] = acc;          // coalesced: lanes write consecutive r
        float s1=acc, s2=acc*acc;
#pragma unroll
        for(int off=32;off>0;off>>=1){ s1+=__shfl_xor(s1,off); s2+=__shfl_xor(s2,off); }
        if(lane==0){ lsum[wid][o]=s1; lsq[wid][o]=s2; }
    }
    __syncthreads();
    if(threadIdx.x<64){
        int o=threadIdx.x;
        atomicAdd(&stats[128+o], lsum[0][o]+lsum[1][o]+lsum[2][o]+lsum[3][o]);
        atomicAdd(&stats[192+o], lsq[0][o]+lsq[1][o]+lsq[2][o]+lsq[3][o]);
    }
}

// ---------------- Layer-2: BN1+ReLU, y2 (not stored): stats2 + per-(b,m,o) max/min over k ----------------
__global__ __launch_bounds__(256) void l2_kernel(
    const float* __restrict__ y1, const float* __restrict__ W2,
    const float* __restrict__ s1, const float* __restrict__ sh1,
    float* __restrict__ maxv, float* __restrict__ minv, float* __restrict__ stats)
{
    const int r = blockIdx.x*256 + threadIdx.x;
    float x1[64];
#pragma unroll
    for(int c=0;c<64;++c)                        // coalesced: lanes read consecutive r
        x1[c] = fmaxf(fmaf(y1[(size_t)c*RROWS + r], s1[c], sh1[c]), 0.f);
    __shared__ float lsum[4][128], lsq[4][128];
    const int lane = threadIdx.x&63, wid = threadIdx.x>>6;
    const size_t g = (size_t)(r>>5);   // (b,m) group: K=32 consecutive rows
    for(int o=0;o<128;++o){
        const float* w = W2 + o*64;
        float acc=0.f;
#pragma unroll
        for(int c=0;c<64;++c) acc = fmaf(x1[c], w[c], acc);
        float mx=acc, mn=acc;
#pragma unroll
        for(int off=16;off>0;off>>=1){ mx=fmaxf(mx,__shfl_xor(mx,off)); mn=fminf(mn,__shfl_xor(mn,off)); }
        float s1v=acc, s2v=acc*acc;
#pragma unroll
        for(int off=32;off>0;off>>=1){ s1v+=__shfl_xor(s1v,off); s2v+=__shfl_xor(s2v,off); }
        if((lane&31)==0){ maxv[g*128+o]=mx; minv[g*128+o]=mn; }
        if(lane==0){ lsum[wid][o]=s1v; lsq[wid][o]=s2v; }
    }
    __syncthreads();
    if(threadIdx.x<128){
        int o=threadIdx.x;
        atomicAdd(&stats[256+o], lsum[0][o]+lsum[1][o]+lsum[2][o]+lsum[3][o]);
        atomicAdd(&stats[384+o], lsq[0][o]+lsq[1][o]+lsq[2][o]+lsq[3][o]);
    }
}

// ---------------- Output: relu(s*pick+sh) where pick = max if s>=0 else min (exact commute) ----------------
__global__ __launch_bounds__(128) void out_kernel(
    const float* __restrict__ maxv, const float* __restrict__ minv,
    const float* __restrict__ s2, const float* __restrict__ sh2,
    float* __restrict__ agg)
{
    const int gg = blockIdx.x;     // 0..B*M-1
    const int o = threadIdx.x;     // 128
    float s = s2[o], sh = sh2[o];
    float pick = (s >= 0.f) ? maxv[(size_t)gg*128+o] : minv[(size_t)gg*128+o];
    float v = fmaxf(fmaf(pick, s, sh), 0.f);
    const int b = gg>>11, m = gg&2047;
    agg[((size_t)b*128 + o)*MM + m] = v;
}

extern "C" void kernel_launch(void* const* d_in, const int* in_sizes, int n_in,
                              void* d_out, int out_size, void* d_ws, size_t ws_size,
                              hipStream_t stream) {
    (void)in_sizes; (void)n_in; (void)out_size; (void)ws_size;
    const float* coords = (const float*)d_in[0];
    const float* feats  = (const float*)d_in[1];
    const float* W0 = (const float*)d_in[2];
    const float* g0 = (const float*)d_in[3];
    const float* b0 = (const float*)d_in[4];
    const float* W1 = (const float*)d_in[5];
    const float* g1 = (const float*)d_in[6];
    const float* b1 = (const float*)d_in[7];
    const float* W2 = (const float*)d_in[8];
    const float* g2 = (const float*)d_in[9];
    const float* b2 = (const float*)d_in[10];

    float* out = (float*)d_out;
    float* anchors = out;                      // [B,M,3]
    float* agg = out + (size_t)BB*MM*3;        // [B,128,M]

    // workspace layout (~73 MB)
    char* ws = (char*)d_ws;
    int*   nb    = (int*)ws;                                       // 262144 ints
    float* y1v   = (float*)(ws + 1048576);                         // 64 x RROWS f32 (transposed)
    float* maxv  = (float*)(ws + 1048576 + 67108864);              // B*M*128
    float* minv  = maxv + (size_t)BB*MM*128;
    float* stats = minv + (size_t)BB*MM*128;                       // 512 floats accum
    float* s0 = stats + 512; float* sh0 = s0 + 64;
    float* s1 = sh0 + 64;    float* sh1 = s1 + 64;
    float* s2 = sh1 + 64;    float* sh2 = s2 + 128;

    hipMemsetAsync(stats, 0, 512*sizeof(float), stream);
    fps_kernel  <<<BB, 512, 0, stream>>>(coords, anchors);
    ballq_kernel<<<BB*MM/4, 256, 0, stream>>>(coords, anchors, nb);
    l0_stats_kernel<<<RROWS/256, 256, 0, stream>>>(coords, feats, anchors, nb, W0, stats);
    fin_kernel  <<<1, 64, 0, stream>>>(stats, g0, b0, s0, sh0, 64);
    l1_kernel   <<<RROWS/256, 256, 0, stream>>>(coords, feats, anchors, nb, W0, W1, s0, sh0, y1v, stats);
    fin_kernel  <<<1, 64, 0, stream>>>(stats+128, g1, b1, s1, sh1, 64);
    l2_kernel   <<<RROWS/256, 256, 0, stream>>>(y1v, W2, s1, sh1, maxv, minv, stats);
    fin_kernel  <<<1, 128, 0, stream>>>(stats+256, g2, b2, s2, sh2, 128);
    out_kernel  <<<BB*MM, 128, 0, stream>>>(maxv, minv, s2, sh2, agg);
}